// Round 16
// baseline (353.444 us; speedup 1.0000x reference)
//
#include <hip/hip_runtime.h>
#include <hip/hip_bf16.h>
#include <cstdint>

#define I_ 16
#define T_ 64
#define Q_ 197
#define K_ 30
#define H_ 8
#define D_ 64
#define E_ 512

typedef float f32x2 __attribute__((ext_vector_type(2)));
typedef float f32x4 __attribute__((ext_vector_type(4)));
typedef short bf16x8 __attribute__((ext_vector_type(8)));

static constexpr float INV_SQRT_E = 0.044194173824159216f;  // 1/sqrt(512)
static constexpr float C197 = 1.0f / 197.0f;
static constexpr int   QK = Q_ * K_;   // 5910

// workspace offsets (in float units)
#define OFF_QBF   0          // bf16 [I,Q,H,D]
#define OFF_KBF   806912     // bf16 [T,K,H,D]
#define OFF_VBF   1298432    // bf16 [T,K,H,D]
#define OFF_TVBF  1789952    // bf16 [I,Q,H,D]
#define OFF_ASUM  2596864    // f32  [I,T,H,K]
#define OFF_TASUM 2842624    // f32  [I,T,H,Q]
#define OFF_PBF   4456448    // bf16 [2048][512]
#define OFF_WBF   4980736    // bf16 [1024][512]
#define OFF_IVR   5242880    // f32  [8192][208]  inv row sums
#define OFF_IVD   6946816    // f32  [8192][32]   inv col denoms

// ---------------- K1: projections; q,k,v,tv -> bf16; W -> bf16 ----------------
__global__ __launch_bounds__(512) void proj_kernel(
    const float* __restrict__ image, const float* __restrict__ text,
    const float* __restrict__ Wq, const float* __restrict__ Wk,
    const float* __restrict__ Wv, const float* __restrict__ Wtv,
    const float* __restrict__ W_out, const float* __restrict__ W_out_text,
    float* __restrict__ ws)
{
  const int NQ4 = (I_ * Q_) / 4;   // 788
  const int NT4 = (T_ * K_) / 4;   // 480
  int bb = blockIdx.x;
  int tid = threadIdx.x;

  if (bb >= NQ4 + 2 * NT4 + NQ4) {           // mode 4: W fp32 -> bf16
    int row0 = (bb - (NQ4 + 2 * NT4 + NQ4)) * 4;
    __hip_bfloat16* Wb = (__hip_bfloat16*)(ws + OFF_WBF);
    const float* src = (row0 < 512) ? (W_out + row0 * E_) : (W_out_text + (row0 - 512) * E_);
    #pragma unroll
    for (int rr = 0; rr < 4; ++rr)
      Wb[(size_t)(row0 + rr) * E_ + tid] = __float2bfloat16(src[rr * E_ + tid]);
    return;
  }

  const float* X; const float* W; int row0; int mode;
  if (bb < NQ4)             { X = image; W = Wq;  row0 = bb * 4;               mode = 0; }
  else if (bb < NQ4 + NT4)  { X = text;  W = Wk;  row0 = (bb - NQ4) * 4;       mode = 1; }
  else if (bb < NQ4 + 2*NT4){ X = text;  W = Wv;  row0 = (bb - NQ4 - NT4) * 4; mode = 2; }
  else                      { X = image; W = Wtv; row0 = (bb - NQ4 - 2*NT4)*4; mode = 3; }

  __shared__ float s_x[4][E_];
  __shared__ float s_w[D_][D_ + 1];
  for (int idx = tid; idx < D_ * D_; idx += 512) s_w[idx >> 6][idx & 63] = W[idx];
  #pragma unroll
  for (int rr = 0; rr < 4; ++rr) s_x[rr][tid] = X[(size_t)(row0 + rr) * E_ + tid];
  __syncthreads();

  int h = tid >> 6, dout = tid & 63;
  float a0 = 0.f, a1 = 0.f, a2 = 0.f, a3 = 0.f;
  #pragma unroll
  for (int d = 0; d < D_; ++d) {
    float w = s_w[dout][d];
    a0 = fmaf(s_x[0][h * 64 + d], w, a0);
    a1 = fmaf(s_x[1][h * 64 + d], w, a1);
    a2 = fmaf(s_x[2][h * 64 + d], w, a2);
    a3 = fmaf(s_x[3][h * 64 + d], w, a3);
  }
  static const int offs[4] = { OFF_QBF, OFF_KBF, OFF_VBF, OFF_TVBF };
  __hip_bfloat16* Y = (__hip_bfloat16*)(ws + offs[mode]);
  Y[(size_t)(row0 + 0) * E_ + tid] = __float2bfloat16(a0);
  Y[(size_t)(row0 + 1) * E_ + tid] = __float2bfloat16(a1);
  Y[(size_t)(row0 + 2) * E_ + tid] = __float2bfloat16(a2);
  Y[(size_t)(row0 + 3) * E_ + tid] = __float2bfloat16(a3);
}

// ---------------- K2a: reduce — invrow, invd, A_sum, TA_sum (no big writes) ----------------
// Wave w owns q-tiles mt = w+4j (mt<13). Lane (lr,lg): q-rows {mt*16+lg*4+r}, k-cols {lr,16+lr}.
__global__ __launch_bounds__(256, 8) void attn_reduce_kernel(
    const __hip_bfloat16* __restrict__ qbf, const __hip_bfloat16* __restrict__ kbf,
    const int* __restrict__ text_mask,
    float* __restrict__ invrow_o, float* __restrict__ invd_o,
    float* __restrict__ A_sum, float* __restrict__ TA_sum)
{
  int b = blockIdx.x;                  // b = ((i*T)+t)*H + h
  int h = b & 7, t = (b >> 3) & 63, i = b >> 9;
  int tid = threadIdx.x;
  int w = tid >> 6, lane = tid & 63;
  int lr = lane & 15, lg = lane >> 4;

  __shared__ float s_cd[4][32];
  __shared__ float s_ca[4][32];
  __shared__ float s_invd[32];

  int m0 = (lr == 0) ? 1 : text_mask[t * (K_ - 1) + lr - 1];
  int m1 = (lr < 14) ? text_mask[t * (K_ - 1) + 15 + lr] : 0;

  const __hip_bfloat16* qb = qbf + ((size_t)(i * Q_) * H_ + h) * D_;
  const __hip_bfloat16* kb = kbf + ((size_t)(t * K_) * H_ + h) * D_;

  const bf16x8* bp0 = (const bf16x8*)(kb + (size_t)lr * (H_ * D_) + lg * 8);
  const bf16x8* bp1 = (const bf16x8*)(kb + (size_t)(16 + lr) * (H_ * D_) + lg * 8);
  bf16x8 b00 = bp0[0], b01 = bp0[4];
  bf16x8 b10 = bp1[0], b11 = bp1[4];

  float cd0 = 0.f, cd1 = 0.f, ca0 = 0.f, ca1 = 0.f;
  f32x4 e0[4], e1[4];                  // f32 e per owned q-tile (static index)

  float* ivr_base = invrow_o + (size_t)b * 208;

  #pragma unroll
  for (int j = 0; j < 4; ++j) {
    int mt = w + 4 * j;
    e0[j] = f32x4{0.f, 0.f, 0.f, 0.f};
    e1[j] = f32x4{0.f, 0.f, 0.f, 0.f};
    if (mt < 13) {
      const bf16x8* ap = (const bf16x8*)(qb + (size_t)(mt * 16 + lr) * (H_ * D_) + lg * 8);
      bf16x8 a0 = ap[0], a1 = ap[4];
      f32x4 acc0 = {0.f, 0.f, 0.f, 0.f}, acc1 = {0.f, 0.f, 0.f, 0.f};
      acc0 = __builtin_amdgcn_mfma_f32_16x16x32_bf16(a0, b00, acc0, 0, 0, 0);
      acc0 = __builtin_amdgcn_mfma_f32_16x16x32_bf16(a1, b01, acc0, 0, 0, 0);
      acc1 = __builtin_amdgcn_mfma_f32_16x16x32_bf16(a0, b10, acc1, 0, 0, 0);
      acc1 = __builtin_amdgcn_mfma_f32_16x16x32_bf16(a1, b11, acc1, 0, 0, 0);
      int row0 = mt * 16 + lg * 4;
      #pragma unroll
      for (int r = 0; r < 4; ++r) {
        bool vr = (row0 + r) < Q_;
        e0[j][r] = (vr && m0) ? __expf(acc0[r] * INV_SQRT_E) : 0.f;
        e1[j][r] = (vr && m1) ? __expf(acc1[r] * INV_SQRT_E) : 0.f;
      }
      #pragma unroll
      for (int r = 0; r < 4; ++r) {
        float s = e0[j][r] + e1[j][r];
        s += __shfl_xor(s, 1);
        s += __shfl_xor(s, 2);
        s += __shfl_xor(s, 4);
        s += __shfl_xor(s, 8);
        float iv = ((row0 + r) < Q_ && s > 0.f) ? (1.0f / s) : 0.f;
        if (lr == 0) ivr_base[row0 + r] = iv;
        cd0 += e0[j][r]; ca0 += e0[j][r] * iv;
        cd1 += e1[j][r]; ca1 += e1[j][r] * iv;
      }
    }
  }

  cd0 += __shfl_xor(cd0, 16); cd0 += __shfl_xor(cd0, 32);
  ca0 += __shfl_xor(ca0, 16); ca0 += __shfl_xor(ca0, 32);
  cd1 += __shfl_xor(cd1, 16); cd1 += __shfl_xor(cd1, 32);
  ca1 += __shfl_xor(ca1, 16); ca1 += __shfl_xor(ca1, 32);
  if (lane < 16) {
    s_cd[w][lr] = cd0; s_cd[w][lr + 16] = cd1;
    s_ca[w][lr] = ca0; s_ca[w][lr + 16] = ca1;
  }
  __syncthreads();

  if (tid < 32) {
    int col = tid;
    float dsum = (s_cd[0][col] + s_cd[1][col]) + (s_cd[2][col] + s_cd[3][col]);
    float pa   = (s_ca[0][col] + s_ca[1][col]) + (s_ca[2][col] + s_ca[3][col]);
    int mc = (col == 0) ? 1 : (col < K_ ? text_mask[t * (K_ - 1) + col - 1] : 0);
    float ivd = (mc && dsum > 0.f) ? (1.0f / dsum) : 0.f;
    s_invd[col] = ivd;
    invd_o[(size_t)b * 32 + col] = ivd;
    if (col < K_) A_sum[(size_t)b * K_ + col] = pa;
  }
  __syncthreads();

  float invd0 = s_invd[lr];
  float invd1 = s_invd[16 + lr];
  float* ta_base = TA_sum + (size_t)b * Q_;

  #pragma unroll
  for (int j = 0; j < 4; ++j) {
    int mt = w + 4 * j;
    if (mt < 13) {
      int row0 = mt * 16 + lg * 4;
      #pragma unroll
      for (int r = 0; r < 4; ++r) {
        float tvA = m0 ? e0[j][r] * invd0 : C197;
        float tvB = (lr < 14) ? (m1 ? e1[j][r] * invd1 : C197) : 0.f;
        float ta = tvA + tvB;
        ta += __shfl_xor(ta, 1);
        ta += __shfl_xor(ta, 2);
        ta += __shfl_xor(ta, 4);
        ta += __shfl_xor(ta, 8);
        if (lr == 0 && (row0 + r) < Q_) ta_base[row0 + r] = ta;
      }
    }
  }
}

// ---------------- K2b: expand — recompute e, scale, pure-stream both tensors ----------------
// ZERO barriers; per-wave LDS staging only; the kernel is as close to a fill as possible.
__global__ __launch_bounds__(256, 8) void attn_expand_kernel(
    const __hip_bfloat16* __restrict__ qbf, const __hip_bfloat16* __restrict__ kbf,
    const int* __restrict__ text_mask,
    const float* __restrict__ invrow_i, const float* __restrict__ invd_i,
    float* __restrict__ attn_out, float* __restrict__ tattn_out)
{
  int b = blockIdx.x;                  // b = ((i*T)+t)*H + h
  int h = b & 7, t = (b >> 3) & 63, i = b >> 9;
  int tid = threadIdx.x;
  int w = tid >> 6, lane = tid & 63;
  int lr = lane & 15, lg = lane >> 4;

  __shared__ __align__(16) float s_stage[4][480];   // per-wave 16x30 staging

  int m0 = (lr == 0) ? 1 : text_mask[t * (K_ - 1) + lr - 1];
  int m1 = (lr < 14) ? text_mask[t * (K_ - 1) + 15 + lr] : 0;

  const __hip_bfloat16* qb = qbf + ((size_t)(i * Q_) * H_ + h) * D_;
  const __hip_bfloat16* kb = kbf + ((size_t)(t * K_) * H_ + h) * D_;

  const bf16x8* bp0 = (const bf16x8*)(kb + (size_t)lr * (H_ * D_) + lg * 8);
  const bf16x8* bp1 = (const bf16x8*)(kb + (size_t)(16 + lr) * (H_ * D_) + lg * 8);
  bf16x8 b00 = bp0[0], b01 = bp0[4];
  bf16x8 b10 = bp1[0], b11 = bp1[4];

  float invd0 = invd_i[(size_t)b * 32 + lr];
  float invd1 = invd_i[(size_t)b * 32 + 16 + lr];
  const float* ivr_base = invrow_i + (size_t)b * 208;

  float* abase = attn_out  + (size_t)b * QK;
  float* tbase = tattn_out + (size_t)b * QK;

  #pragma unroll
  for (int j = 0; j < 4; ++j) {
    int mt = w + 4 * j;
    if (mt < 13) {
      const bf16x8* ap = (const bf16x8*)(qb + (size_t)(mt * 16 + lr) * (H_ * D_) + lg * 8);
      bf16x8 a0 = ap[0], a1 = ap[4];
      f32x4 acc0 = {0.f, 0.f, 0.f, 0.f}, acc1 = {0.f, 0.f, 0.f, 0.f};
      acc0 = __builtin_amdgcn_mfma_f32_16x16x32_bf16(a0, b00, acc0, 0, 0, 0);
      acc0 = __builtin_amdgcn_mfma_f32_16x16x32_bf16(a1, b01, acc0, 0, 0, 0);
      acc1 = __builtin_amdgcn_mfma_f32_16x16x32_bf16(a0, b10, acc1, 0, 0, 0);
      acc1 = __builtin_amdgcn_mfma_f32_16x16x32_bf16(a1, b11, acc1, 0, 0, 0);
      int row0 = mt * 16 + lg * 4;
      float v0[4], v1[4], iv[4];
      #pragma unroll
      for (int r = 0; r < 4; ++r) {
        bool vr = (row0 + r) < Q_;
        v0[r] = (vr && m0) ? __expf(acc0[r] * INV_SQRT_E) : 0.f;
        v1[r] = (vr && m1) ? __expf(acc1[r] * INV_SQRT_E) : 0.f;
        iv[r] = ivr_base[row0 + r];    // broadcast load (same addr across lr)
      }
      // stage + stream a-tile
      #pragma unroll
      for (int r = 0; r < 4; ++r) {
        int rl = lg * 4 + r;
        s_stage[w][rl * K_ + lr] = v0[r] * iv[r];
        if (lr < 14) s_stage[w][rl * K_ + 16 + lr] = v1[r] * iv[r];
      }
      const int nstore = (mt < 12) ? 240 : 75;
      #pragma unroll
      for (int it = 0; it < 4; ++it) {
        int idx = it * 64 + lane;
        if (idx < nstore) {
          f32x2 a2 = *(const f32x2*)&s_stage[w][2 * idx];
          *(f32x2*)(abase + mt * 480 + 2 * idx) = a2;
        }
      }
      // stage + stream t-tile
      #pragma unroll
      for (int r = 0; r < 4; ++r) {
        int rl = lg * 4 + r;
        s_stage[w][rl * K_ + lr] = m0 ? v0[r] * invd0 : C197;
        if (lr < 14) s_stage[w][rl * K_ + 16 + lr] = m1 ? v1[r] * invd1 : C197;
      }
      #pragma unroll
      for (int it = 0; it < 4; ++it) {
        int idx = it * 64 + lane;
        if (idx < nstore) {
          f32x2 t2 = *(const f32x2*)&s_stage[w][2 * idx];
          *(f32x2*)(tbase + mt * 480 + 2 * idx) = t2;
        }
      }
    }
  }
}

// ---------------- K3: fused pooled i2t + t2i -> Pbf ----------------
__global__ __launch_bounds__(512) void pool_fused_kernel(
    const float* __restrict__ A_sum, const float* __restrict__ TA_sum,
    const __hip_bfloat16* __restrict__ vbf, const __hip_bfloat16* __restrict__ tvbf,
    __hip_bfloat16* __restrict__ Pbf)
{
  int bt = blockIdx.x;           // i*T + t
  int t = bt & 63;
  int i = bt >> 6;
  int tid = threadIdx.x;
  int h = tid >> 6, d = tid & 63;
  __shared__ float s_A[H_ * K_];
  __shared__ float s_TA[H_ * Q_];
  if (tid < H_ * K_) s_A[tid] = A_sum[(size_t)bt * H_ * K_ + tid];
  for (int idx = tid; idx < H_ * Q_; idx += 512) s_TA[idx] = TA_sum[(size_t)bt * H_ * Q_ + idx];
  __syncthreads();

  {
    float a0 = 0.f, a1 = 0.f;
    #pragma unroll
    for (int kk = 0; kk < K_; kk += 2) {
      a0 = fmaf(s_A[h * K_ + kk],
                __bfloat162float(vbf[((size_t)(t * K_ + kk)     * H_ + h) * D_ + d]), a0);
      a1 = fmaf(s_A[h * K_ + kk + 1],
                __bfloat162float(vbf[((size_t)(t * K_ + kk + 1) * H_ + h) * D_ + d]), a1);
    }
    Pbf[(size_t)bt * E_ + tid] = __float2bfloat16((a0 + a1) * C197);
  }

  {
    float a0 = 0.f, a1 = 0.f, a2 = 0.f, a3 = 0.f;
    int qq = 0;
    for (; qq + 4 <= Q_; qq += 4) {
      a0 = fmaf(s_TA[h * Q_ + qq + 0],
                __bfloat162float(tvbf[((size_t)(i * Q_ + qq + 0) * H_ + h) * D_ + d]), a0);
      a1 = fmaf(s_TA[h * Q_ + qq + 1],
                __bfloat162float(tvbf[((size_t)(i * Q_ + qq + 1) * H_ + h) * D_ + d]), a1);
      a2 = fmaf(s_TA[h * Q_ + qq + 2],
                __bfloat162float(tvbf[((size_t)(i * Q_ + qq + 2) * H_ + h) * D_ + d]), a2);
      a3 = fmaf(s_TA[h * Q_ + qq + 3],
                __bfloat162float(tvbf[((size_t)(i * Q_ + qq + 3) * H_ + h) * D_ + d]), a3);
    }
    for (; qq < Q_; ++qq)
      a0 = fmaf(s_TA[h * Q_ + qq],
                __bfloat162float(tvbf[((size_t)(i * Q_ + qq) * H_ + h) * D_ + d]), a0);
    Pbf[(size_t)(1024 + bt) * E_ + tid] = __float2bfloat16(((a0 + a1) + (a2 + a3)) * (1.0f / 30.0f));
  }
}

// ---------------- K4: MFMA out-projection ----------------
__global__ __launch_bounds__(256) void outproj_mfma_kernel(
    const __hip_bfloat16* __restrict__ Pbf, const __hip_bfloat16* __restrict__ Wbf,
    const float* __restrict__ b_out, const float* __restrict__ b_out_text,
    float* __restrict__ out)
{
  int mt = blockIdx.x;             // 0..127
  int z = (mt >= 64);
  int tid = threadIdx.x;
  int w = tid >> 6, lane = tid & 63;
  int lr = lane & 15, lg = lane >> 4;

  const __hip_bfloat16* A = Pbf + (size_t)(mt * 16 + lr) * E_ + lg * 8;
  const __hip_bfloat16* B = Wbf + (size_t)(z * 512) * E_;
  f32x4 acc[8] = {};
  for (int ks = 0; ks < 16; ++ks) {
    bf16x8 a = *(const bf16x8*)(A + ks * 32);
    #pragma unroll
    for (int nt = 0; nt < 8; ++nt) {
      int n0 = w * 128 + nt * 16;
      bf16x8 bv = *(const bf16x8*)(B + (size_t)(n0 + lr) * E_ + ks * 32 + lg * 8);
      acc[nt] = __builtin_amdgcn_mfma_f32_16x16x32_bf16(a, bv, acc[nt], 0, 0, 0);
    }
  }
  const float* bias = z ? b_out_text : b_out;
  int row0 = mt * 16 + lg * 4;
  #pragma unroll
  for (int nt = 0; nt < 8; ++nt) {
    int n = w * 128 + nt * 16 + lr;
    float bv = bias[n];
    #pragma unroll
    for (int r = 0; r < 4; ++r)
      out[(size_t)(row0 + r) * E_ + n] = acc[nt][r] + bv;
  }
}

extern "C" void kernel_launch(void* const* d_in, const int* in_sizes, int n_in,
                              void* d_out, int out_size, void* d_ws, size_t ws_size,
                              hipStream_t stream)
{
  const float* image      = (const float*)d_in[0];
  const float* text       = (const float*)d_in[1];
  const int*   tmask      = (const int*)d_in[2];
  const float* Wq         = (const float*)d_in[3];
  const float* Wk         = (const float*)d_in[4];
  const float* Wv         = (const float*)d_in[5];
  const float* W_out      = (const float*)d_in[6];
  const float* b_out      = (const float*)d_in[7];
  const float* Wtv        = (const float*)d_in[8];
  const float* W_out_text = (const float*)d_in[9];
  const float* b_out_text = (const float*)d_in[10];

  float* out = (float*)d_out;
  float* ws  = (float*)d_ws;

  const __hip_bfloat16* qbf  = (const __hip_bfloat16*)(ws + OFF_QBF);
  const __hip_bfloat16* kbf  = (const __hip_bfloat16*)(ws + OFF_KBF);
  const __hip_bfloat16* vbf  = (const __hip_bfloat16*)(ws + OFF_VBF);
  const __hip_bfloat16* tvbf = (const __hip_bfloat16*)(ws + OFF_TVBF);
  float* Asum  = ws + OFF_ASUM;
  float* TAsum = ws + OFF_TASUM;
  __hip_bfloat16* Pbf = (__hip_bfloat16*)(ws + OFF_PBF);
  __hip_bfloat16* Wbf = (__hip_bfloat16*)(ws + OFF_WBF);
  float* ivr  = ws + OFF_IVR;
  float* ivd  = ws + OFF_IVD;

  float* attn    = out + (size_t)2 * I_ * T_ * E_;        // [I,T,H,Q,K]
  float* tattn   = attn + (size_t)I_ * T_ * H_ * Q_ * K_; // [I,T,H,Q,K]

  const int NQ4 = (I_ * Q_) / 4, NT4 = (T_ * K_) / 4;
  proj_kernel<<<NQ4 + 2 * NT4 + NQ4 + 256, 512, 0, stream>>>(
      image, text, Wq, Wk, Wv, Wtv, W_out, W_out_text, ws);
  attn_reduce_kernel<<<I_ * T_ * H_, 256, 0, stream>>>(qbf, kbf, tmask, ivr, ivd, Asum, TAsum);
  attn_expand_kernel<<<I_ * T_ * H_, 256, 0, stream>>>(qbf, kbf, tmask, ivr, ivd, attn, tattn);
  pool_fused_kernel<<<I_ * T_, 512, 0, stream>>>(Asum, TAsum, vbf, tvbf, Pbf);
  outproj_mfma_kernel<<<128, 256, 0, stream>>>(Pbf, Wbf, b_out, b_out_text, out);
}

// Round 17
// 310.586 us; speedup vs baseline: 1.1380x; 1.1380x over previous
//
#include <hip/hip_runtime.h>
#include <hip/hip_bf16.h>
#include <cstdint>

#define I_ 16
#define T_ 64
#define Q_ 197
#define K_ 30
#define H_ 8
#define D_ 64
#define E_ 512

typedef float f32x2 __attribute__((ext_vector_type(2)));
typedef float f32x4 __attribute__((ext_vector_type(4)));
typedef short bf16x8 __attribute__((ext_vector_type(8)));

static constexpr float INV_SQRT_E = 0.044194173824159216f;  // 1/sqrt(512)
static constexpr float C197 = 1.0f / 197.0f;
static constexpr int   QK = Q_ * K_;   // 5910

// workspace offsets (in float units)
#define OFF_QBF   0          // bf16 [I,Q,H,D]
#define OFF_KBF   806912     // bf16 [T,K,H,D]
#define OFF_VBF   1298432    // bf16 [T,K,H,D]
#define OFF_TVBF  1789952    // bf16 [I,Q,H,D]
#define OFF_ASUM  2596864    // f32  [I,T,H,K]
#define OFF_TASUM 2842624    // f32  [I,T,H,Q]
#define OFF_PBF   4456448    // bf16 [2048][512]
#define OFF_WBF   4980736    // bf16 [1024][512]

__device__ inline short f2bs(float x) { __hip_bfloat16 h = __float2bfloat16(x); return *reinterpret_cast<short*>(&h); }
__device__ inline float bs2f(short s) { __hip_bfloat16 h = *reinterpret_cast<__hip_bfloat16*>(&s); return __bfloat162float(h); }

// ---------------- K1: projections; q,k,v,tv -> bf16; W -> bf16 ----------------
__global__ __launch_bounds__(512) void proj_kernel(
    const float* __restrict__ image, const float* __restrict__ text,
    const float* __restrict__ Wq, const float* __restrict__ Wk,
    const float* __restrict__ Wv, const float* __restrict__ Wtv,
    const float* __restrict__ W_out, const float* __restrict__ W_out_text,
    float* __restrict__ ws)
{
  const int NQ4 = (I_ * Q_) / 4;   // 788
  const int NT4 = (T_ * K_) / 4;   // 480
  int bb = blockIdx.x;
  int tid = threadIdx.x;

  if (bb >= NQ4 + 2 * NT4 + NQ4) {           // mode 4: W fp32 -> bf16
    int row0 = (bb - (NQ4 + 2 * NT4 + NQ4)) * 4;
    __hip_bfloat16* Wb = (__hip_bfloat16*)(ws + OFF_WBF);
    const float* src = (row0 < 512) ? (W_out + row0 * E_) : (W_out_text + (row0 - 512) * E_);
    #pragma unroll
    for (int rr = 0; rr < 4; ++rr)
      Wb[(size_t)(row0 + rr) * E_ + tid] = __float2bfloat16(src[rr * E_ + tid]);
    return;
  }

  const float* X; const float* W; int row0; int mode;
  if (bb < NQ4)             { X = image; W = Wq;  row0 = bb * 4;               mode = 0; }
  else if (bb < NQ4 + NT4)  { X = text;  W = Wk;  row0 = (bb - NQ4) * 4;       mode = 1; }
  else if (bb < NQ4 + 2*NT4){ X = text;  W = Wv;  row0 = (bb - NQ4 - NT4) * 4; mode = 2; }
  else                      { X = image; W = Wtv; row0 = (bb - NQ4 - 2*NT4)*4; mode = 3; }

  __shared__ float s_x[4][E_];
  __shared__ float s_w[D_][D_ + 1];
  for (int idx = tid; idx < D_ * D_; idx += 512) s_w[idx >> 6][idx & 63] = W[idx];
  #pragma unroll
  for (int rr = 0; rr < 4; ++rr) s_x[rr][tid] = X[(size_t)(row0 + rr) * E_ + tid];
  __syncthreads();

  int h = tid >> 6, dout = tid & 63;
  float a0 = 0.f, a1 = 0.f, a2 = 0.f, a3 = 0.f;
  #pragma unroll
  for (int d = 0; d < D_; ++d) {
    float w = s_w[dout][d];
    a0 = fmaf(s_x[0][h * 64 + d], w, a0);
    a1 = fmaf(s_x[1][h * 64 + d], w, a1);
    a2 = fmaf(s_x[2][h * 64 + d], w, a2);
    a3 = fmaf(s_x[3][h * 64 + d], w, a3);
  }
  static const int offs[4] = { OFF_QBF, OFF_KBF, OFF_VBF, OFF_TVBF };
  __hip_bfloat16* Y = (__hip_bfloat16*)(ws + offs[mode]);
  Y[(size_t)(row0 + 0) * E_ + tid] = __float2bfloat16(a0);
  Y[(size_t)(row0 + 1) * E_ + tid] = __float2bfloat16(a1);
  Y[(size_t)(row0 + 2) * E_ + tid] = __float2bfloat16(a2);
  Y[(size_t)(row0 + 3) * E_ + tid] = __float2bfloat16(a3);
}

// ---------------- K2: PERSISTENT MFMA attention (round-15 body, 4 b's per block) ----------------
__global__ __launch_bounds__(256, 8) void attn_kernel(
    const __hip_bfloat16* __restrict__ qbf, const __hip_bfloat16* __restrict__ kbf,
    const int* __restrict__ text_mask,
    float* __restrict__ attn_out, float* __restrict__ tattn_out,
    float* __restrict__ A_sum, float* __restrict__ TA_sum)
{
  int tid = threadIdx.x;
  int w = tid >> 6, lane = tid & 63;
  int lr = lane & 15, lg = lane >> 4;

  __shared__ __align__(16) float s_stage[4][480];   // per-wave 16x30 staging
  __shared__ float s_cd[4][32];
  __shared__ float s_ca[4][32];
  __shared__ float s_invd[32];

  for (int it = 0; it < 4; ++it) {
    int b = it * 2048 + blockIdx.x;    // b = ((i*T)+t)*H + h
    int h = b & 7, t = (b >> 3) & 63, i = b >> 9;

    int m0 = (lr == 0) ? 1 : text_mask[t * (K_ - 1) + lr - 1];
    int m1 = (lr < 14) ? text_mask[t * (K_ - 1) + 15 + lr] : 0;

    const __hip_bfloat16* qb = qbf + ((size_t)(i * Q_) * H_ + h) * D_;
    const __hip_bfloat16* kb = kbf + ((size_t)(t * K_) * H_ + h) * D_;

    const bf16x8* bp0 = (const bf16x8*)(kb + (size_t)lr * (H_ * D_) + lg * 8);
    const bf16x8* bp1 = (const bf16x8*)(kb + (size_t)(16 + lr) * (H_ * D_) + lg * 8);
    bf16x8 b00 = bp0[0], b01 = bp0[4];
    bf16x8 b10 = bp1[0], b11 = bp1[4];

    float* abase = attn_out  + (size_t)b * QK;
    float* tbase = tattn_out + (size_t)b * QK;

    float cd0 = 0.f, cd1 = 0.f, ca0 = 0.f, ca1 = 0.f;
    bf16x8 epk[4];

    // ---- pass 1: MFMA + exp + row softmax; stream a-tensor per tile ----
    #pragma unroll
    for (int j = 0; j < 4; ++j) {
      int mt = w + 4 * j;
      epk[j] = bf16x8{0, 0, 0, 0, 0, 0, 0, 0};
      if (mt < 13) {
        const bf16x8* ap = (const bf16x8*)(qb + (size_t)(mt * 16 + lr) * (H_ * D_) + lg * 8);
        bf16x8 a0 = ap[0], a1 = ap[4];
        f32x4 acc0 = {0.f, 0.f, 0.f, 0.f}, acc1 = {0.f, 0.f, 0.f, 0.f};
        acc0 = __builtin_amdgcn_mfma_f32_16x16x32_bf16(a0, b00, acc0, 0, 0, 0);
        acc0 = __builtin_amdgcn_mfma_f32_16x16x32_bf16(a1, b01, acc0, 0, 0, 0);
        acc1 = __builtin_amdgcn_mfma_f32_16x16x32_bf16(a0, b10, acc1, 0, 0, 0);
        acc1 = __builtin_amdgcn_mfma_f32_16x16x32_bf16(a1, b11, acc1, 0, 0, 0);
        int row0 = mt * 16 + lg * 4;
        float v0[4], v1[4], iv[4];
        #pragma unroll
        for (int r = 0; r < 4; ++r) {
          bool vr = (row0 + r) < Q_;
          v0[r] = (vr && m0) ? __expf(acc0[r] * INV_SQRT_E) : 0.f;
          v1[r] = (vr && m1) ? __expf(acc1[r] * INV_SQRT_E) : 0.f;
        }
        #pragma unroll
        for (int r = 0; r < 4; ++r) {
          float s = v0[r] + v1[r];
          s += __shfl_xor(s, 1);
          s += __shfl_xor(s, 2);
          s += __shfl_xor(s, 4);
          s += __shfl_xor(s, 8);
          iv[r] = ((row0 + r) < Q_ && s > 0.f) ? (1.0f / s) : 0.f;
          cd0 += v0[r]; ca0 += v0[r] * iv[r];
          cd1 += v1[r]; ca1 += v1[r] * iv[r];
        }
        #pragma unroll
        for (int r = 0; r < 4; ++r) {
          int rl = lg * 4 + r;
          s_stage[w][rl * K_ + lr] = v0[r] * iv[r];
          if (lr < 14) s_stage[w][rl * K_ + 16 + lr] = v1[r] * iv[r];
        }
        epk[j] = bf16x8{ f2bs(v0[0]), f2bs(v0[1]), f2bs(v0[2]), f2bs(v0[3]),
                         f2bs(v1[0]), f2bs(v1[1]), f2bs(v1[2]), f2bs(v1[3]) };
        const int nstore = (mt < 12) ? 240 : 75;
        #pragma unroll
        for (int it2 = 0; it2 < 4; ++it2) {
          int idx = it2 * 64 + lane;
          if (idx < nstore) {
            f32x2 a2 = *(const f32x2*)&s_stage[w][2 * idx];
            *(f32x2*)(abase + mt * 480 + 2 * idx) = a2;
          }
        }
      }
    }

    // ---- column totals + cross-wave exchange ----
    cd0 += __shfl_xor(cd0, 16); cd0 += __shfl_xor(cd0, 32);
    ca0 += __shfl_xor(ca0, 16); ca0 += __shfl_xor(ca0, 32);
    cd1 += __shfl_xor(cd1, 16); cd1 += __shfl_xor(cd1, 32);
    ca1 += __shfl_xor(ca1, 16); ca1 += __shfl_xor(ca1, 32);
    if (lane < 16) {
      s_cd[w][lr] = cd0; s_cd[w][lr + 16] = cd1;
      s_ca[w][lr] = ca0; s_ca[w][lr + 16] = ca1;
    }
    __syncthreads();

    if (tid < 32) {
      int col = tid;
      float dsum = (s_cd[0][col] + s_cd[1][col]) + (s_cd[2][col] + s_cd[3][col]);
      float pa   = (s_ca[0][col] + s_ca[1][col]) + (s_ca[2][col] + s_ca[3][col]);
      int mc = (col == 0) ? 1 : (col < K_ ? text_mask[t * (K_ - 1) + col - 1] : 0);
      s_invd[col] = (mc && dsum > 0.f) ? (1.0f / dsum) : 0.f;
      if (col < K_) A_sum[(size_t)b * K_ + col] = pa;
    }
    __syncthreads();

    float invd0 = s_invd[lr];
    float invd1 = s_invd[16 + lr];
    float* ta_base = TA_sum + (size_t)b * Q_;

    // ---- pass 2: t-tensor per tile (+ TA row sums) ----
    #pragma unroll
    for (int j = 0; j < 4; ++j) {
      int mt = w + 4 * j;
      if (mt < 13) {
        int row0 = mt * 16 + lg * 4;
        float tvA[4], tvB[4];
        #pragma unroll
        for (int r = 0; r < 4; ++r) {
          float eA = bs2f(epk[j][r]);
          float eB = bs2f(epk[j][4 + r]);
          tvA[r] = m0 ? eA * invd0 : C197;
          tvB[r] = m1 ? eB * invd1 : C197;
          int rl = lg * 4 + r;
          s_stage[w][rl * K_ + lr] = tvA[r];
          if (lr < 14) s_stage[w][rl * K_ + 16 + lr] = tvB[r];
        }
        #pragma unroll
        for (int r = 0; r < 4; ++r) {
          float ta = tvA[r] + ((lr < 14) ? tvB[r] : 0.f);
          ta += __shfl_xor(ta, 1);
          ta += __shfl_xor(ta, 2);
          ta += __shfl_xor(ta, 4);
          ta += __shfl_xor(ta, 8);
          if (lr == 0 && (row0 + r) < Q_) ta_base[row0 + r] = ta;
        }
        const int nstore = (mt < 12) ? 240 : 75;
        #pragma unroll
        for (int it2 = 0; it2 < 4; ++it2) {
          int idx = it2 * 64 + lane;
          if (idx < nstore) {
            f32x2 t2 = *(const f32x2*)&s_stage[w][2 * idx];
            *(f32x2*)(tbase + mt * 480 + 2 * idx) = t2;
          }
        }
      }
    }
    __syncthreads();   // protect s_stage/s_cd reuse before next iteration
  }
}

// ---------------- K3: fused pooled i2t + t2i -> Pbf ----------------
__global__ __launch_bounds__(512) void pool_fused_kernel(
    const float* __restrict__ A_sum, const float* __restrict__ TA_sum,
    const __hip_bfloat16* __restrict__ vbf, const __hip_bfloat16* __restrict__ tvbf,
    __hip_bfloat16* __restrict__ Pbf)
{
  int bt = blockIdx.x;           // i*T + t
  int t = bt & 63;
  int i = bt >> 6;
  int tid = threadIdx.x;
  int h = tid >> 6, d = tid & 63;
  __shared__ float s_A[H_ * K_];
  __shared__ float s_TA[H_ * Q_];
  if (tid < H_ * K_) s_A[tid] = A_sum[(size_t)bt * H_ * K_ + tid];
  for (int idx = tid; idx < H_ * Q_; idx += 512) s_TA[idx] = TA_sum[(size_t)bt * H_ * Q_ + idx];
  __syncthreads();

  {
    float a0 = 0.f, a1 = 0.f;
    #pragma unroll
    for (int kk = 0; kk < K_; kk += 2) {
      a0 = fmaf(s_A[h * K_ + kk],
                __bfloat162float(vbf[((size_t)(t * K_ + kk)     * H_ + h) * D_ + d]), a0);
      a1 = fmaf(s_A[h * K_ + kk + 1],
                __bfloat162float(vbf[((size_t)(t * K_ + kk + 1) * H_ + h) * D_ + d]), a1);
    }
    Pbf[(size_t)bt * E_ + tid] = __float2bfloat16((a0 + a1) * C197);
  }

  {
    float a0 = 0.f, a1 = 0.f, a2 = 0.f, a3 = 0.f;
    int qq = 0;
    for (; qq + 4 <= Q_; qq += 4) {
      a0 = fmaf(s_TA[h * Q_ + qq + 0],
                __bfloat162float(tvbf[((size_t)(i * Q_ + qq + 0) * H_ + h) * D_ + d]), a0);
      a1 = fmaf(s_TA[h * Q_ + qq + 1],
                __bfloat162float(tvbf[((size_t)(i * Q_ + qq + 1) * H_ + h) * D_ + d]), a1);
      a2 = fmaf(s_TA[h * Q_ + qq + 2],
                __bfloat162float(tvbf[((size_t)(i * Q_ + qq + 2) * H_ + h) * D_ + d]), a2);
      a3 = fmaf(s_TA[h * Q_ + qq + 3],
                __bfloat162float(tvbf[((size_t)(i * Q_ + qq + 3) * H_ + h) * D_ + d]), a3);
    }
    for (; qq < Q_; ++qq)
      a0 = fmaf(s_TA[h * Q_ + qq],
                __bfloat162float(tvbf[((size_t)(i * Q_ + qq) * H_ + h) * D_ + d]), a0);
    Pbf[(size_t)(1024 + bt) * E_ + tid] = __float2bfloat16(((a0 + a1) + (a2 + a3)) * (1.0f / 30.0f));
  }
}

// ---------------- K4: MFMA out-projection ----------------
__global__ __launch_bounds__(256) void outproj_mfma_kernel(
    const __hip_bfloat16* __restrict__ Pbf, const __hip_bfloat16* __restrict__ Wbf,
    const float* __restrict__ b_out, const float* __restrict__ b_out_text,
    float* __restrict__ out)
{
  int mt = blockIdx.x;             // 0..127
  int z = (mt >= 64);
  int tid = threadIdx.x;
  int w = tid >> 6, lane = tid & 63;
  int lr = lane & 15, lg = lane >> 4;

  const __hip_bfloat16* A = Pbf + (size_t)(mt * 16 + lr) * E_ + lg * 8;
  const __hip_bfloat16* B = Wbf + (size_t)(z * 512) * E_;
  f32x4 acc[8] = {};
  for (int ks = 0; ks < 16; ++ks) {
    bf16x8 a = *(const bf16x8*)(A + ks * 32);
    #pragma unroll
    for (int nt = 0; nt < 8; ++nt) {
      int n0 = w * 128 + nt * 16;
      bf16x8 bv = *(const bf16x8*)(B + (size_t)(n0 + lr) * E_ + ks * 32 + lg * 8);
      acc[nt] = __builtin_amdgcn_mfma_f32_16x16x32_bf16(a, bv, acc[nt], 0, 0, 0);
    }
  }
  const float* bias = z ? b_out_text : b_out;
  int row0 = mt * 16 + lg * 4;
  #pragma unroll
  for (int nt = 0; nt < 8; ++nt) {
    int n = w * 128 + nt * 16 + lr;
    float bv = bias[n];
    #pragma unroll
    for (int r = 0; r < 4; ++r)
      out[(size_t)(row0 + r) * E_ + n] = acc[nt][r] + bv;
  }
}

extern "C" void kernel_launch(void* const* d_in, const int* in_sizes, int n_in,
                              void* d_out, int out_size, void* d_ws, size_t ws_size,
                              hipStream_t stream)
{
  const float* image      = (const float*)d_in[0];
  const float* text       = (const float*)d_in[1];
  const int*   tmask      = (const int*)d_in[2];
  const float* Wq         = (const float*)d_in[3];
  const float* Wk         = (const float*)d_in[4];
  const float* Wv         = (const float*)d_in[5];
  const float* W_out      = (const float*)d_in[6];
  const float* b_out      = (const float*)d_in[7];
  const float* Wtv        = (const float*)d_in[8];
  const float* W_out_text = (const float*)d_in[9];
  const float* b_out_text = (const float*)d_in[10];

  float* out = (float*)d_out;
  float* ws  = (float*)d_ws;

  const __hip_bfloat16* qbf  = (const __hip_bfloat16*)(ws + OFF_QBF);
  const __hip_bfloat16* kbf  = (const __hip_bfloat16*)(ws + OFF_KBF);
  const __hip_bfloat16* vbf  = (const __hip_bfloat16*)(ws + OFF_VBF);
  const __hip_bfloat16* tvbf = (const __hip_bfloat16*)(ws + OFF_TVBF);
  float* Asum  = ws + OFF_ASUM;
  float* TAsum = ws + OFF_TASUM;
  __hip_bfloat16* Pbf = (__hip_bfloat16*)(ws + OFF_PBF);
  __hip_bfloat16* Wbf = (__hip_bfloat16*)(ws + OFF_WBF);

  float* attn    = out + (size_t)2 * I_ * T_ * E_;        // [I,T,H,Q,K]
  float* tattn   = attn + (size_t)I_ * T_ * H_ * Q_ * K_; // [I,T,H,Q,K]

  const int NQ4 = (I_ * Q_) / 4, NT4 = (T_ * K_) / 4;
  proj_kernel<<<NQ4 + 2 * NT4 + NQ4 + 256, 512, 0, stream>>>(
      image, text, Wq, Wk, Wv, Wtv, W_out, W_out_text, ws);
  attn_kernel<<<2048, 256, 0, stream>>>(qbf, kbf, tmask, attn, tattn, Asum, TAsum);
  pool_fused_kernel<<<I_ * T_, 512, 0, stream>>>(Asum, TAsum, vbf, tvbf, Pbf);
  outproj_mfma_kernel<<<128, 256, 0, stream>>>(Pbf, Wbf, b_out, b_out_text, out);
}

// Round 18
// 193.018 us; speedup vs baseline: 1.8311x; 1.6091x over previous
//
#include <hip/hip_runtime.h>
#include <hip/hip_bf16.h>
#include <cstdint>

#define I_ 16
#define T_ 64
#define Q_ 197
#define K_ 30
#define H_ 8
#define D_ 64
#define E_ 512

typedef float f32x2 __attribute__((ext_vector_type(2)));
typedef float f32x4 __attribute__((ext_vector_type(4)));
typedef short bf16x8 __attribute__((ext_vector_type(8)));

static constexpr float INV_SQRT_E = 0.044194173824159216f;  // 1/sqrt(512)
static constexpr float C197 = 1.0f / 197.0f;
static constexpr int   QK = Q_ * K_;   // 5910

// workspace offsets (in float units)
#define OFF_QBF   0          // bf16 [I,Q,H,D]
#define OFF_KBF   806912     // bf16 [T,K,H,D]
#define OFF_VBF   1298432    // bf16 [T,K,H,D]
#define OFF_TVBF  1789952    // bf16 [I,Q,H,D]
#define OFF_ASUM  2596864    // f32  [I,T,H,K]
#define OFF_TASUM 2842624    // f32  [I,T,H,Q]
#define OFF_PBF   4456448    // bf16 [2048][512]
#define OFF_WBF   4980736    // bf16 [1024][512]

// ---------------- K1: projections; q,k,v,tv -> bf16; W -> bf16 ----------------
__global__ __launch_bounds__(512) void proj_kernel(
    const float* __restrict__ image, const float* __restrict__ text,
    const float* __restrict__ Wq, const float* __restrict__ Wk,
    const float* __restrict__ Wv, const float* __restrict__ Wtv,
    const float* __restrict__ W_out, const float* __restrict__ W_out_text,
    float* __restrict__ ws)
{
  const int NQ4 = (I_ * Q_) / 4;   // 788
  const int NT4 = (T_ * K_) / 4;   // 480
  int bb = blockIdx.x;
  int tid = threadIdx.x;

  if (bb >= NQ4 + 2 * NT4 + NQ4) {           // mode 4: W fp32 -> bf16
    int row0 = (bb - (NQ4 + 2 * NT4 + NQ4)) * 4;
    __hip_bfloat16* Wb = (__hip_bfloat16*)(ws + OFF_WBF);
    const float* src = (row0 < 512) ? (W_out + row0 * E_) : (W_out_text + (row0 - 512) * E_);
    #pragma unroll
    for (int rr = 0; rr < 4; ++rr)
      Wb[(size_t)(row0 + rr) * E_ + tid] = __float2bfloat16(src[rr * E_ + tid]);
    return;
  }

  const float* X; const float* W; int row0; int mode;
  if (bb < NQ4)             { X = image; W = Wq;  row0 = bb * 4;               mode = 0; }
  else if (bb < NQ4 + NT4)  { X = text;  W = Wk;  row0 = (bb - NQ4) * 4;       mode = 1; }
  else if (bb < NQ4 + 2*NT4){ X = text;  W = Wv;  row0 = (bb - NQ4 - NT4) * 4; mode = 2; }
  else                      { X = image; W = Wtv; row0 = (bb - NQ4 - 2*NT4)*4; mode = 3; }

  __shared__ float s_x[4][E_];
  __shared__ float s_w[D_][D_ + 1];
  for (int idx = tid; idx < D_ * D_; idx += 512) s_w[idx >> 6][idx & 63] = W[idx];
  #pragma unroll
  for (int rr = 0; rr < 4; ++rr) s_x[rr][tid] = X[(size_t)(row0 + rr) * E_ + tid];
  __syncthreads();

  int h = tid >> 6, dout = tid & 63;
  float a0 = 0.f, a1 = 0.f, a2 = 0.f, a3 = 0.f;
  #pragma unroll
  for (int d = 0; d < D_; ++d) {
    float w = s_w[dout][d];
    a0 = fmaf(s_x[0][h * 64 + d], w, a0);
    a1 = fmaf(s_x[1][h * 64 + d], w, a1);
    a2 = fmaf(s_x[2][h * 64 + d], w, a2);
    a3 = fmaf(s_x[3][h * 64 + d], w, a3);
  }
  static const int offs[4] = { OFF_QBF, OFF_KBF, OFF_VBF, OFF_TVBF };
  __hip_bfloat16* Y = (__hip_bfloat16*)(ws + offs[mode]);
  Y[(size_t)(row0 + 0) * E_ + tid] = __float2bfloat16(a0);
  Y[(size_t)(row0 + 1) * E_ + tid] = __float2bfloat16(a1);
  Y[(size_t)(row0 + 2) * E_ + tid] = __float2bfloat16(a2);
  Y[(size_t)(row0 + 3) * E_ + tid] = __float2bfloat16(a3);
}

// ---------------- K2: register MFMA attention + bf16 LDS e-tile + 64B-ALIGNED f4 epilogue ----------------
// Identical to round 13 except: the flat copy-out body is 64-byte-line-aligned
// (runtime head of 0..15 floats), plain cached f32x4 stores — the fill-kernel store
// shape that rocprof shows avoids read-for-ownership (FETCH ~0).
__global__ __launch_bounds__(256, 8) void attn_kernel(
    const __hip_bfloat16* __restrict__ qbf, const __hip_bfloat16* __restrict__ kbf,
    const int* __restrict__ text_mask,
    float* __restrict__ attn_out, float* __restrict__ tattn_out,
    float* __restrict__ A_sum, float* __restrict__ TA_sum)
{
  int b = blockIdx.x;                  // b = ((i*T)+t)*H + h
  int h = b & 7, t = (b >> 3) & 63, i = b >> 9;
  int tid = threadIdx.x;
  int w = tid >> 6, lane = tid & 63;
  int lr = lane & 15, lg = lane >> 4;

  __shared__ __hip_bfloat16 s_e[208 * 30];   // 12,480 B raw exp tile (bf16; masked = 0)
  __shared__ float s_invrow[208];
  __shared__ float s_cd[4][32];
  __shared__ float s_ca[4][32];
  __shared__ float s_invd[32];
  __shared__ int   s_mask[32];

  if (tid < 32) s_mask[tid] = (tid == 0) ? 1 : (tid < K_ ? text_mask[t * (K_ - 1) + tid - 1] : 0);

  int m0 = (lr == 0) ? 1 : text_mask[t * (K_ - 1) + lr - 1];
  int m1 = (lr < 14) ? text_mask[t * (K_ - 1) + 15 + lr] : 0;

  const __hip_bfloat16* qb = qbf + ((size_t)(i * Q_) * H_ + h) * D_;  // row stride 512
  const __hip_bfloat16* kb = kbf + ((size_t)(t * K_) * H_ + h) * D_;

  const bf16x8* bp0 = (const bf16x8*)(kb + (size_t)lr * (H_ * D_) + lg * 8);
  const bf16x8* bp1 = (const bf16x8*)(kb + (size_t)(16 + lr) * (H_ * D_) + lg * 8);
  bf16x8 b00 = bp0[0], b01 = bp0[4];
  bf16x8 b10 = bp1[0], b11 = bp1[4];

  float cd0 = 0.f, cd1 = 0.f, ca0 = 0.f, ca1 = 0.f;

  #pragma unroll
  for (int j = 0; j < 4; ++j) {
    int mt = w + 4 * j;
    if (mt < 13) {
      const bf16x8* ap = (const bf16x8*)(qb + (size_t)(mt * 16 + lr) * (H_ * D_) + lg * 8);
      bf16x8 a0 = ap[0], a1 = ap[4];
      f32x4 acc0 = {0.f, 0.f, 0.f, 0.f}, acc1 = {0.f, 0.f, 0.f, 0.f};
      acc0 = __builtin_amdgcn_mfma_f32_16x16x32_bf16(a0, b00, acc0, 0, 0, 0);
      acc0 = __builtin_amdgcn_mfma_f32_16x16x32_bf16(a1, b01, acc0, 0, 0, 0);
      acc1 = __builtin_amdgcn_mfma_f32_16x16x32_bf16(a0, b10, acc1, 0, 0, 0);
      acc1 = __builtin_amdgcn_mfma_f32_16x16x32_bf16(a1, b11, acc1, 0, 0, 0);
      int row0 = mt * 16 + lg * 4;
      float v0[4], v1[4];
      #pragma unroll
      for (int r = 0; r < 4; ++r) {
        bool vr = (row0 + r) < Q_;
        v0[r] = (vr && m0) ? __expf(acc0[r] * INV_SQRT_E) : 0.f;
        v1[r] = (vr && m1) ? __expf(acc1[r] * INV_SQRT_E) : 0.f;
        s_e[(row0 + r) * K_ + lr] = __float2bfloat16(v0[r]);
        if (lr < 14) s_e[(row0 + r) * K_ + 16 + lr] = __float2bfloat16(v1[r]);
      }
      #pragma unroll
      for (int r = 0; r < 4; ++r) {
        float s = v0[r] + v1[r];
        s += __shfl_xor(s, 1);
        s += __shfl_xor(s, 2);
        s += __shfl_xor(s, 4);
        s += __shfl_xor(s, 8);
        float iv = ((row0 + r) < Q_ && s > 0.f) ? (1.0f / s) : 0.f;
        if (lr == 0) s_invrow[row0 + r] = iv;
        cd0 += v0[r]; ca0 += v0[r] * iv;
        cd1 += v1[r]; ca1 += v1[r] * iv;
      }
    }
  }

  cd0 += __shfl_xor(cd0, 16); cd0 += __shfl_xor(cd0, 32);
  ca0 += __shfl_xor(ca0, 16); ca0 += __shfl_xor(ca0, 32);
  cd1 += __shfl_xor(cd1, 16); cd1 += __shfl_xor(cd1, 32);
  ca1 += __shfl_xor(ca1, 16); ca1 += __shfl_xor(ca1, 32);
  if (lane < 16) {
    s_cd[w][lr] = cd0; s_cd[w][lr + 16] = cd1;
    s_ca[w][lr] = ca0; s_ca[w][lr + 16] = ca1;
  }
  __syncthreads();

  if (tid < 32) {
    int col = tid;
    float d  = s_cd[0][col] + s_cd[1][col] + s_cd[2][col] + s_cd[3][col];
    float pa = s_ca[0][col] + s_ca[1][col] + s_ca[2][col] + s_ca[3][col];
    s_invd[col] = (s_mask[col] && d > 0.f) ? (1.0f / d) : 0.f;
    if (col < K_) A_sum[(size_t)b * K_ + col] = pa;
  }
  __syncthreads();

  // TA_sum per row (masked col contributes exactly 1/197)
  if (tid < Q_) {
    float ta = 0.f;
    #pragma unroll
    for (int kk = 0; kk < K_; ++kk) {
      float ev = __bfloat162float(s_e[tid * K_ + kk]);
      ta += s_mask[kk] ? ev * s_invd[kk] : C197;
    }
    TA_sum[(size_t)b * Q_ + tid] = ta;
  }

  // ---- flat copy-out, 64B-aligned f32x4 body (fill-kernel store shape) ----
  {
    float* abase = attn_out  + (size_t)b * QK;
    float* tbase = tattn_out + (size_t)b * QK;
    // (b*QK) % 16 floats == (6b)&15; head floats bring body to a 64B boundary
    int head  = (16 - ((b * 6) & 15)) & 15;
    int nbody = (QK - head) >> 2;
    int tail0 = head + (nbody << 2);
    int ntail = QK - tail0;            // 0..3
    if (tid < head + ntail) {
      int idx = (tid < head) ? tid : (tail0 + tid - head);
      float ev = __bfloat162float(s_e[idx]);
      int rw = idx / K_, cl = idx - rw * K_;
      abase[idx] = ev * s_invrow[rw];
      tbase[idx] = s_mask[cl] ? ev * s_invd[cl] : C197;
    }
    for (int fi = tid; fi < nbody; fi += 256) {
      int base = head + fi * 4;
      float ev[4]; int rw[4]; int cl[4];
      #pragma unroll
      for (int e = 0; e < 4; ++e) {
        int idx = base + e;
        ev[e] = __bfloat162float(s_e[idx]);
        rw[e] = idx / K_;
        cl[e] = idx - rw[e] * K_;
      }
      f32x4 av, tv4;
      #pragma unroll
      for (int e = 0; e < 4; ++e) {
        av[e]  = ev[e] * s_invrow[rw[e]];
        tv4[e] = s_mask[cl[e]] ? ev[e] * s_invd[cl[e]] : C197;
      }
      *(f32x4*)(abase + base) = av;
      *(f32x4*)(tbase + base) = tv4;
    }
  }
}

// ---------------- K3: fused pooled i2t + t2i -> Pbf (bf16; v/tv read as bf16) ----------------
__global__ __launch_bounds__(512) void pool_fused_kernel(
    const float* __restrict__ A_sum, const float* __restrict__ TA_sum,
    const __hip_bfloat16* __restrict__ vbf, const __hip_bfloat16* __restrict__ tvbf,
    __hip_bfloat16* __restrict__ Pbf)
{
  int bt = blockIdx.x;           // i*T + t
  int t = bt & 63;
  int i = bt >> 6;
  int tid = threadIdx.x;
  int h = tid >> 6, d = tid & 63;
  __shared__ float s_A[H_ * K_];
  __shared__ float s_TA[H_ * Q_];
  if (tid < H_ * K_) s_A[tid] = A_sum[(size_t)bt * H_ * K_ + tid];
  for (int idx = tid; idx < H_ * Q_; idx += 512) s_TA[idx] = TA_sum[(size_t)bt * H_ * Q_ + idx];
  __syncthreads();

  {
    float a0 = 0.f, a1 = 0.f;
    #pragma unroll
    for (int kk = 0; kk < K_; kk += 2) {
      a0 = fmaf(s_A[h * K_ + kk],
                __bfloat162float(vbf[((size_t)(t * K_ + kk)     * H_ + h) * D_ + d]), a0);
      a1 = fmaf(s_A[h * K_ + kk + 1],
                __bfloat162float(vbf[((size_t)(t * K_ + kk + 1) * H_ + h) * D_ + d]), a1);
    }
    Pbf[(size_t)bt * E_ + tid] = __float2bfloat16((a0 + a1) * C197);
  }

  {
    float a0 = 0.f, a1 = 0.f, a2 = 0.f, a3 = 0.f;
    int qq = 0;
    for (; qq + 4 <= Q_; qq += 4) {
      a0 = fmaf(s_TA[h * Q_ + qq + 0],
                __bfloat162float(tvbf[((size_t)(i * Q_ + qq + 0) * H_ + h) * D_ + d]), a0);
      a1 = fmaf(s_TA[h * Q_ + qq + 1],
                __bfloat162float(tvbf[((size_t)(i * Q_ + qq + 1) * H_ + h) * D_ + d]), a1);
      a2 = fmaf(s_TA[h * Q_ + qq + 2],
                __bfloat162float(tvbf[((size_t)(i * Q_ + qq + 2) * H_ + h) * D_ + d]), a2);
      a3 = fmaf(s_TA[h * Q_ + qq + 3],
                __bfloat162float(tvbf[((size_t)(i * Q_ + qq + 3) * H_ + h) * D_ + d]), a3);
    }
    for (; qq < Q_; ++qq)
      a0 = fmaf(s_TA[h * Q_ + qq],
                __bfloat162float(tvbf[((size_t)(i * Q_ + qq) * H_ + h) * D_ + d]), a0);
    Pbf[(size_t)(1024 + bt) * E_ + tid] = __float2bfloat16(((a0 + a1) + (a2 + a3)) * (1.0f / 30.0f));
  }
}

// ---------------- K4: MFMA out-projection ----------------
__global__ __launch_bounds__(256) void outproj_mfma_kernel(
    const __hip_bfloat16* __restrict__ Pbf, const __hip_bfloat16* __restrict__ Wbf,
    const float* __restrict__ b_out, const float* __restrict__ b_out_text,
    float* __restrict__ out)
{
  int mt = blockIdx.x;             // 0..127
  int z = (mt >= 64);
  int tid = threadIdx.x;
  int w = tid >> 6, lane = tid & 63;
  int lr = lane & 15, lg = lane >> 4;

  const __hip_bfloat16* A = Pbf + (size_t)(mt * 16 + lr) * E_ + lg * 8;
  const __hip_bfloat16* B = Wbf + (size_t)(z * 512) * E_;
  f32x4 acc[8] = {};
  for (int ks = 0; ks < 16; ++ks) {
    bf16x8 a = *(const bf16x8*)(A + ks * 32);
    #pragma unroll
    for (int nt = 0; nt < 8; ++nt) {
      int n0 = w * 128 + nt * 16;
      bf16x8 bv = *(const bf16x8*)(B + (size_t)(n0 + lr) * E_ + ks * 32 + lg * 8);
      acc[nt] = __builtin_amdgcn_mfma_f32_16x16x32_bf16(a, bv, acc[nt], 0, 0, 0);
    }
  }
  const float* bias = z ? b_out_text : b_out;
  int row0 = mt * 16 + lg * 4;
  #pragma unroll
  for (int nt = 0; nt < 8; ++nt) {
    int n = w * 128 + nt * 16 + lr;
    float bv = bias[n];
    #pragma unroll
    for (int r = 0; r < 4; ++r)
      out[(size_t)(row0 + r) * E_ + n] = acc[nt][r] + bv;
  }
}

extern "C" void kernel_launch(void* const* d_in, const int* in_sizes, int n_in,
                              void* d_out, int out_size, void* d_ws, size_t ws_size,
                              hipStream_t stream)
{
  const float* image      = (const float*)d_in[0];
  const float* text       = (const float*)d_in[1];
  const int*   tmask      = (const int*)d_in[2];
  const float* Wq         = (const float*)d_in[3];
  const float* Wk         = (const float*)d_in[4];
  const float* Wv         = (const float*)d_in[5];
  const float* W_out      = (const float*)d_in[6];
  const float* b_out      = (const float*)d_in[7];
  const float* Wtv        = (const float*)d_in[8];
  const float* W_out_text = (const float*)d_in[9];
  const float* b_out_text = (const float*)d_in[10];

  float* out = (float*)d_out;
  float* ws  = (float*)d_ws;

  const __hip_bfloat16* qbf  = (const __hip_bfloat16*)(ws + OFF_QBF);
  const __hip_bfloat16* kbf  = (const __hip_bfloat16*)(ws + OFF_KBF);
  const __hip_bfloat16* vbf  = (const __hip_bfloat16*)(ws + OFF_VBF);
  const __hip_bfloat16* tvbf = (const __hip_bfloat16*)(ws + OFF_TVBF);
  float* Asum  = ws + OFF_ASUM;
  float* TAsum = ws + OFF_TASUM;
  __hip_bfloat16* Pbf = (__hip_bfloat16*)(ws + OFF_PBF);
  __hip_bfloat16* Wbf = (__hip_bfloat16*)(ws + OFF_WBF);

  float* attn    = out + (size_t)2 * I_ * T_ * E_;        // [I,T,H,Q,K]
  float* tattn   = attn + (size_t)I_ * T_ * H_ * Q_ * K_; // [I,T,H,Q,K]

  const int NQ4 = (I_ * Q_) / 4, NT4 = (T_ * K_) / 4;
  proj_kernel<<<NQ4 + 2 * NT4 + NQ4 + 256, 512, 0, stream>>>(
      image, text, Wq, Wk, Wv, Wtv, W_out, W_out_text, ws);
  attn_kernel<<<I_ * T_ * H_, 256, 0, stream>>>(qbf, kbf, tmask, attn, tattn, Asum, TAsum);
  pool_fused_kernel<<<I_ * T_, 512, 0, stream>>>(Asum, TAsum, vbf, tvbf, Pbf);
  outproj_mfma_kernel<<<128, 256, 0, stream>>>(Pbf, Wbf, b_out, b_out_text, out);
}

// Round 19
// 185.890 us; speedup vs baseline: 1.9014x; 1.0383x over previous
//
#include <hip/hip_runtime.h>
#include <hip/hip_bf16.h>
#include <cstdint>

#define I_ 16
#define T_ 64
#define Q_ 197
#define K_ 30
#define H_ 8
#define D_ 64
#define E_ 512

typedef float f32x2 __attribute__((ext_vector_type(2)));
typedef float f32x4 __attribute__((ext_vector_type(4)));
typedef short bf16x8 __attribute__((ext_vector_type(8)));

static constexpr float INV_SQRT_E = 0.044194173824159216f;  // 1/sqrt(512)
static constexpr float C197 = 1.0f / 197.0f;
static constexpr int   QK = Q_ * K_;   // 5910

// workspace offsets (in float units)
#define OFF_QBF   0          // bf16 [I,Q,H,D]
#define OFF_KBF   806912     // bf16 [T,K,H,D]
#define OFF_VBF   1298432    // bf16 [T,K,H,D]
#define OFF_TVBF  1789952    // bf16 [I,Q,H,D]
#define OFF_ASUM  2596864    // f32  [I,T,H,K]
#define OFF_TASUM 2842624    // f32  [I,T,H,Q]
#define OFF_PBF   4456448    // bf16 [2048][512]
#define OFF_WBF   4980736    // bf16 [1024][512]

__device__ inline short f2bs(float x) { __hip_bfloat16 h = __float2bfloat16(x); return *reinterpret_cast<short*>(&h); }
__device__ inline float bs2f(short s) { __hip_bfloat16 h = *reinterpret_cast<__hip_bfloat16*>(&s); return __bfloat162float(h); }

// ---------------- K1: projections; q,k,v,tv -> bf16; W -> bf16 ----------------
__global__ __launch_bounds__(512) void proj_kernel(
    const float* __restrict__ image, const float* __restrict__ text,
    const float* __restrict__ Wq, const float* __restrict__ Wk,
    const float* __restrict__ Wv, const float* __restrict__ Wtv,
    const float* __restrict__ W_out, const float* __restrict__ W_out_text,
    float* __restrict__ ws)
{
  const int NQ4 = (I_ * Q_) / 4;   // 788
  const int NT4 = (T_ * K_) / 4;   // 480
  int bb = blockIdx.x;
  int tid = threadIdx.x;

  if (bb >= NQ4 + 2 * NT4 + NQ4) {           // mode 4: W fp32 -> bf16
    int row0 = (bb - (NQ4 + 2 * NT4 + NQ4)) * 4;
    __hip_bfloat16* Wb = (__hip_bfloat16*)(ws + OFF_WBF);
    const float* src = (row0 < 512) ? (W_out + row0 * E_) : (W_out_text + (row0 - 512) * E_);
    #pragma unroll
    for (int rr = 0; rr < 4; ++rr)
      Wb[(size_t)(row0 + rr) * E_ + tid] = __float2bfloat16(src[rr * E_ + tid]);
    return;
  }

  const float* X; const float* W; int row0; int mode;
  if (bb < NQ4)             { X = image; W = Wq;  row0 = bb * 4;               mode = 0; }
  else if (bb < NQ4 + NT4)  { X = text;  W = Wk;  row0 = (bb - NQ4) * 4;       mode = 1; }
  else if (bb < NQ4 + 2*NT4){ X = text;  W = Wv;  row0 = (bb - NQ4 - NT4) * 4; mode = 2; }
  else                      { X = image; W = Wtv; row0 = (bb - NQ4 - 2*NT4)*4; mode = 3; }

  __shared__ float s_x[4][E_];
  __shared__ float s_w[D_][D_ + 1];
  for (int idx = tid; idx < D_ * D_; idx += 512) s_w[idx >> 6][idx & 63] = W[idx];
  #pragma unroll
  for (int rr = 0; rr < 4; ++rr) s_x[rr][tid] = X[(size_t)(row0 + rr) * E_ + tid];
  __syncthreads();

  int h = tid >> 6, dout = tid & 63;
  float a0 = 0.f, a1 = 0.f, a2 = 0.f, a3 = 0.f;
  #pragma unroll
  for (int d = 0; d < D_; ++d) {
    float w = s_w[dout][d];
    a0 = fmaf(s_x[0][h * 64 + d], w, a0);
    a1 = fmaf(s_x[1][h * 64 + d], w, a1);
    a2 = fmaf(s_x[2][h * 64 + d], w, a2);
    a3 = fmaf(s_x[3][h * 64 + d], w, a3);
  }
  static const int offs[4] = { OFF_QBF, OFF_KBF, OFF_VBF, OFF_TVBF };
  __hip_bfloat16* Y = (__hip_bfloat16*)(ws + offs[mode]);
  Y[(size_t)(row0 + 0) * E_ + tid] = __float2bfloat16(a0);
  Y[(size_t)(row0 + 1) * E_ + tid] = __float2bfloat16(a1);
  Y[(size_t)(row0 + 2) * E_ + tid] = __float2bfloat16(a2);
  Y[(size_t)(row0 + 3) * E_ + tid] = __float2bfloat16(a3);
}

// ---------------- K2: round-15 streamed attention + XCD-contiguous block swizzle ----------------
// Swizzle: block n -> b = (n&7)*1024 + (n>>3). XCD x owns b in [x*1024, x*1024+1024):
// output region XCD-private; q-slices (2 i-values) + all k L2-resident per XCD.
__global__ __launch_bounds__(256, 8) void attn_kernel(
    const __hip_bfloat16* __restrict__ qbf, const __hip_bfloat16* __restrict__ kbf,
    const int* __restrict__ text_mask,
    float* __restrict__ attn_out, float* __restrict__ tattn_out,
    float* __restrict__ A_sum, float* __restrict__ TA_sum)
{
  int n = blockIdx.x;
  int b = ((n & 7) << 10) + (n >> 3);  // b = ((i*T)+t)*H + h
  int h = b & 7, t = (b >> 3) & 63, i = b >> 9;
  int tid = threadIdx.x;
  int w = tid >> 6, lane = tid & 63;
  int lr = lane & 15, lg = lane >> 4;

  __shared__ __align__(16) float s_stage[4][480];   // per-wave 16x30 staging
  __shared__ float s_cd[4][32];
  __shared__ float s_ca[4][32];
  __shared__ float s_invd[32];

  int m0 = (lr == 0) ? 1 : text_mask[t * (K_ - 1) + lr - 1];
  int m1 = (lr < 14) ? text_mask[t * (K_ - 1) + 15 + lr] : 0;

  const __hip_bfloat16* qb = qbf + ((size_t)(i * Q_) * H_ + h) * D_;  // row stride 512
  const __hip_bfloat16* kb = kbf + ((size_t)(t * K_) * H_ + h) * D_;

  const bf16x8* bp0 = (const bf16x8*)(kb + (size_t)lr * (H_ * D_) + lg * 8);
  const bf16x8* bp1 = (const bf16x8*)(kb + (size_t)(16 + lr) * (H_ * D_) + lg * 8);
  bf16x8 b00 = bp0[0], b01 = bp0[4];
  bf16x8 b10 = bp1[0], b11 = bp1[4];

  float* abase = attn_out  + (size_t)b * QK;
  float* tbase = tattn_out + (size_t)b * QK;

  float cd0 = 0.f, cd1 = 0.f, ca0 = 0.f, ca1 = 0.f;
  bf16x8 epk[4];                       // packed e per owned q-tile (static index)

  // ---- pass 1: MFMA + exp + row softmax; stream a-tensor per tile ----
  #pragma unroll
  for (int j = 0; j < 4; ++j) {
    int mt = w + 4 * j;
    epk[j] = bf16x8{0, 0, 0, 0, 0, 0, 0, 0};
    if (mt < 13) {
      const bf16x8* ap = (const bf16x8*)(qb + (size_t)(mt * 16 + lr) * (H_ * D_) + lg * 8);
      bf16x8 a0 = ap[0], a1 = ap[4];
      f32x4 acc0 = {0.f, 0.f, 0.f, 0.f}, acc1 = {0.f, 0.f, 0.f, 0.f};
      acc0 = __builtin_amdgcn_mfma_f32_16x16x32_bf16(a0, b00, acc0, 0, 0, 0);
      acc0 = __builtin_amdgcn_mfma_f32_16x16x32_bf16(a1, b01, acc0, 0, 0, 0);
      acc1 = __builtin_amdgcn_mfma_f32_16x16x32_bf16(a0, b10, acc1, 0, 0, 0);
      acc1 = __builtin_amdgcn_mfma_f32_16x16x32_bf16(a1, b11, acc1, 0, 0, 0);
      int row0 = mt * 16 + lg * 4;
      float v0[4], v1[4], iv[4];
      #pragma unroll
      for (int r = 0; r < 4; ++r) {
        bool vr = (row0 + r) < Q_;
        v0[r] = (vr && m0) ? __expf(acc0[r] * INV_SQRT_E) : 0.f;
        v1[r] = (vr && m1) ? __expf(acc1[r] * INV_SQRT_E) : 0.f;
      }
      #pragma unroll
      for (int r = 0; r < 4; ++r) {
        float s = v0[r] + v1[r];
        s += __shfl_xor(s, 1);
        s += __shfl_xor(s, 2);
        s += __shfl_xor(s, 4);
        s += __shfl_xor(s, 8);
        iv[r] = ((row0 + r) < Q_ && s > 0.f) ? (1.0f / s) : 0.f;
        cd0 += v0[r]; ca0 += v0[r] * iv[r];
        cd1 += v1[r]; ca1 += v1[r] * iv[r];
      }
      #pragma unroll
      for (int r = 0; r < 4; ++r) {
        int rl = lg * 4 + r;
        s_stage[w][rl * K_ + lr] = v0[r] * iv[r];
        if (lr < 14) s_stage[w][rl * K_ + 16 + lr] = v1[r] * iv[r];
      }
      epk[j] = bf16x8{ f2bs(v0[0]), f2bs(v0[1]), f2bs(v0[2]), f2bs(v0[3]),
                       f2bs(v1[0]), f2bs(v1[1]), f2bs(v1[2]), f2bs(v1[3]) };
      const int nstore = (mt < 12) ? 240 : 75;
      #pragma unroll
      for (int it2 = 0; it2 < 4; ++it2) {
        int idx = it2 * 64 + lane;
        if (idx < nstore) {
          f32x2 a2 = *(const f32x2*)&s_stage[w][2 * idx];
          *(f32x2*)(abase + mt * 480 + 2 * idx) = a2;
        }
      }
    }
  }

  // ---- column totals + cross-wave exchange ----
  cd0 += __shfl_xor(cd0, 16); cd0 += __shfl_xor(cd0, 32);
  ca0 += __shfl_xor(ca0, 16); ca0 += __shfl_xor(ca0, 32);
  cd1 += __shfl_xor(cd1, 16); cd1 += __shfl_xor(cd1, 32);
  ca1 += __shfl_xor(ca1, 16); ca1 += __shfl_xor(ca1, 32);
  if (lane < 16) {
    s_cd[w][lr] = cd0; s_cd[w][lr + 16] = cd1;
    s_ca[w][lr] = ca0; s_ca[w][lr + 16] = ca1;
  }
  __syncthreads();

  if (tid < 32) {
    int col = tid;
    float dsum = (s_cd[0][col] + s_cd[1][col]) + (s_cd[2][col] + s_cd[3][col]);
    float pa   = (s_ca[0][col] + s_ca[1][col]) + (s_ca[2][col] + s_ca[3][col]);
    int mc = (col == 0) ? 1 : (col < K_ ? text_mask[t * (K_ - 1) + col - 1] : 0);
    s_invd[col] = (mc && dsum > 0.f) ? (1.0f / dsum) : 0.f;
    if (col < K_) A_sum[(size_t)b * K_ + col] = pa;
  }
  __syncthreads();

  float invd0 = s_invd[lr];
  float invd1 = s_invd[16 + lr];
  float* ta_base = TA_sum + (size_t)b * Q_;

  // ---- pass 2: t-tensor per tile (+ TA row sums via shfl) ----
  #pragma unroll
  for (int j = 0; j < 4; ++j) {
    int mt = w + 4 * j;
    if (mt < 13) {
      int row0 = mt * 16 + lg * 4;
      float tvA[4], tvB[4];
      #pragma unroll
      for (int r = 0; r < 4; ++r) {
        float eA = bs2f(epk[j][r]);
        float eB = bs2f(epk[j][4 + r]);
        tvA[r] = m0 ? eA * invd0 : C197;
        tvB[r] = m1 ? eB * invd1 : C197;
        int rl = lg * 4 + r;
        s_stage[w][rl * K_ + lr] = tvA[r];
        if (lr < 14) s_stage[w][rl * K_ + 16 + lr] = tvB[r];
      }
      #pragma unroll
      for (int r = 0; r < 4; ++r) {
        float ta = tvA[r] + ((lr < 14) ? tvB[r] : 0.f);
        ta += __shfl_xor(ta, 1);
        ta += __shfl_xor(ta, 2);
        ta += __shfl_xor(ta, 4);
        ta += __shfl_xor(ta, 8);
        if (lr == 0 && (row0 + r) < Q_) ta_base[row0 + r] = ta;
      }
      const int nstore = (mt < 12) ? 240 : 75;
      #pragma unroll
      for (int it2 = 0; it2 < 4; ++it2) {
        int idx = it2 * 64 + lane;
        if (idx < nstore) {
          f32x2 t2 = *(const f32x2*)&s_stage[w][2 * idx];
          *(f32x2*)(tbase + mt * 480 + 2 * idx) = t2;
        }
      }
    }
  }
}

// ---------------- K3: fused pooled i2t + t2i -> Pbf ----------------
__global__ __launch_bounds__(512) void pool_fused_kernel(
    const float* __restrict__ A_sum, const float* __restrict__ TA_sum,
    const __hip_bfloat16* __restrict__ vbf, const __hip_bfloat16* __restrict__ tvbf,
    __hip_bfloat16* __restrict__ Pbf)
{
  int bt = blockIdx.x;           // i*T + t
  int t = bt & 63;
  int i = bt >> 6;
  int tid = threadIdx.x;
  int h = tid >> 6, d = tid & 63;
  __shared__ float s_A[H_ * K_];
  __shared__ float s_TA[H_ * Q_];
  if (tid < H_ * K_) s_A[tid] = A_sum[(size_t)bt * H_ * K_ + tid];
  for (int idx = tid; idx < H_ * Q_; idx += 512) s_TA[idx] = TA_sum[(size_t)bt * H_ * Q_ + idx];
  __syncthreads();

  {
    float a0 = 0.f, a1 = 0.f;
    #pragma unroll
    for (int kk = 0; kk < K_; kk += 2) {
      a0 = fmaf(s_A[h * K_ + kk],
                __bfloat162float(vbf[((size_t)(t * K_ + kk)     * H_ + h) * D_ + d]), a0);
      a1 = fmaf(s_A[h * K_ + kk + 1],
                __bfloat162float(vbf[((size_t)(t * K_ + kk + 1) * H_ + h) * D_ + d]), a1);
    }
    Pbf[(size_t)bt * E_ + tid] = __float2bfloat16((a0 + a1) * C197);
  }

  {
    float a0 = 0.f, a1 = 0.f, a2 = 0.f, a3 = 0.f;
    int qq = 0;
    for (; qq + 4 <= Q_; qq += 4) {
      a0 = fmaf(s_TA[h * Q_ + qq + 0],
                __bfloat162float(tvbf[((size_t)(i * Q_ + qq + 0) * H_ + h) * D_ + d]), a0);
      a1 = fmaf(s_TA[h * Q_ + qq + 1],
                __bfloat162float(tvbf[((size_t)(i * Q_ + qq + 1) * H_ + h) * D_ + d]), a1);
      a2 = fmaf(s_TA[h * Q_ + qq + 2],
                __bfloat162float(tvbf[((size_t)(i * Q_ + qq + 2) * H_ + h) * D_ + d]), a2);
      a3 = fmaf(s_TA[h * Q_ + qq + 3],
                __bfloat162float(tvbf[((size_t)(i * Q_ + qq + 3) * H_ + h) * D_ + d]), a3);
    }
    for (; qq < Q_; ++qq)
      a0 = fmaf(s_TA[h * Q_ + qq],
                __bfloat162float(tvbf[((size_t)(i * Q_ + qq) * H_ + h) * D_ + d]), a0);
    Pbf[(size_t)(1024 + bt) * E_ + tid] = __float2bfloat16(((a0 + a1) + (a2 + a3)) * (1.0f / 30.0f));
  }
}

// ---------------- K4: MFMA out-projection ----------------
__global__ __launch_bounds__(256) void outproj_mfma_kernel(
    const __hip_bfloat16* __restrict__ Pbf, const __hip_bfloat16* __restrict__ Wbf,
    const float* __restrict__ b_out, const float* __restrict__ b_out_text,
    float* __restrict__ out)
{
  int mt = blockIdx.x;             // 0..127
  int z = (mt >= 64);
  int tid = threadIdx.x;
  int w = tid >> 6, lane = tid & 63;
  int lr = lane & 15, lg = lane >> 4;

  const __hip_bfloat16* A = Pbf + (size_t)(mt * 16 + lr) * E_ + lg * 8;
  const __hip_bfloat16* B = Wbf + (size_t)(z * 512) * E_;
  f32x4 acc[8] = {};
  for (int ks = 0; ks < 16; ++ks) {
    bf16x8 a = *(const bf16x8*)(A + ks * 32);
    #pragma unroll
    for (int nt = 0; nt < 8; ++nt) {
      int n0 = w * 128 + nt * 16;
      bf16x8 bv = *(const bf16x8*)(B + (size_t)(n0 + lr) * E_ + ks * 32 + lg * 8);
      acc[nt] = __builtin_amdgcn_mfma_f32_16x16x32_bf16(a, bv, acc[nt], 0, 0, 0);
    }
  }
  const float* bias = z ? b_out_text : b_out;
  int row0 = mt * 16 + lg * 4;
  #pragma unroll
  for (int nt = 0; nt < 8; ++nt) {
    int n = w * 128 + nt * 16 + lr;
    float bv = bias[n];
    #pragma unroll
    for (int r = 0; r < 4; ++r)
      out[(size_t)(row0 + r) * E_ + n] = acc[nt][r] + bv;
  }
}

extern "C" void kernel_launch(void* const* d_in, const int* in_sizes, int n_in,
                              void* d_out, int out_size, void* d_ws, size_t ws_size,
                              hipStream_t stream)
{
  const float* image      = (const float*)d_in[0];
  const float* text       = (const float*)d_in[1];
  const int*   tmask      = (const int*)d_in[2];
  const float* Wq         = (const float*)d_in[3];
  const float* Wk         = (const float*)d_in[4];
  const float* Wv         = (const float*)d_in[5];
  const float* W_out      = (const float*)d_in[6];
  const float* b_out      = (const float*)d_in[7];
  const float* Wtv        = (const float*)d_in[8];
  const float* W_out_text = (const float*)d_in[9];
  const float* b_out_text = (const float*)d_in[10];

  float* out = (float*)d_out;
  float* ws  = (float*)d_ws;

  const __hip_bfloat16* qbf  = (const __hip_bfloat16*)(ws + OFF_QBF);
  const __hip_bfloat16* kbf  = (const __hip_bfloat16*)(ws + OFF_KBF);
  const __hip_bfloat16* vbf  = (const __hip_bfloat16*)(ws + OFF_VBF);
  const __hip_bfloat16* tvbf = (const __hip_bfloat16*)(ws + OFF_TVBF);
  float* Asum  = ws + OFF_ASUM;
  float* TAsum = ws + OFF_TASUM;
  __hip_bfloat16* Pbf = (__hip_bfloat16*)(ws + OFF_PBF);
  __hip_bfloat16* Wbf = (__hip_bfloat16*)(ws + OFF_WBF);

  float* attn    = out + (size_t)2 * I_ * T_ * E_;        // [I,T,H,Q,K]
  float* tattn   = attn + (size_t)I_ * T_ * H_ * Q_ * K_; // [I,T,H,Q,K]

  const int NQ4 = (I_ * Q_) / 4, NT4 = (T_ * K_) / 4;
  proj_kernel<<<NQ4 + 2 * NT4 + NQ4 + 256, 512, 0, stream>>>(
      image, text, Wq, Wk, Wv, Wtv, W_out, W_out_text, ws);
  attn_kernel<<<I_ * T_ * H_, 256, 0, stream>>>(qbf, kbf, tmask, attn, tattn, Asum, TAsum);
  pool_fused_kernel<<<I_ * T_, 512, 0, stream>>>(Asum, TAsum, vbf, tvbf, Pbf);
  outproj_mfma_kernel<<<128, 256, 0, stream>>>(Pbf, Wbf, b_out, b_out_text, out);
}